// Round 21
// baseline (89.218 us; speedup 1.0000x reference)
//
#include <hip/hip_runtime.h>
#include <hip/hip_fp16.h>
#include <hip/hip_bf16.h>

using u16 = unsigned short;
using u32 = unsigned int;
typedef float f32x4 __attribute__((ext_vector_type(4)));
typedef _Float16 h16x2 __attribute__((ext_vector_type(2)));
typedef _Float16 f16x8 __attribute__((ext_vector_type(8)));

// ---- helpers ----------------------------------------------------------------
// RNE f32 -> f16 bits
static __device__ __forceinline__ u16 f2h(float f) {
  __half h = __float2half(f);
  u16 r;
  __builtin_memcpy(&r, &h, 2);
  return r;
}

// RNE pack of two f32 -> f16x2 (a in low half)
static __device__ __forceinline__ u32 pack2h(float a, float b) {
  return (u32)f2h(a) | ((u32)f2h(b) << 16);
}

static __device__ __forceinline__ f16x8 as_h8(uint4 v) {
  f16x8 r;
  __builtin_memcpy(&r, &v, 16);
  return r;
}

static __device__ __forceinline__ h16x2 as_h2(u32 v) {
  h16x2 r;
  __builtin_memcpy(&r, &v, 4);
  return r;
}

static __device__ __forceinline__ u32 h2bits(h16x2 v) {
  u32 r;
  __builtin_memcpy(&r, &v, 4);
  return r;
}

// 4-corner bilinear blend of 8 f16 channels, fully packed-f16 math
static __device__ __forceinline__ uint4 blend4h(uint4 a, uint4 b, uint4 c, uint4 d,
                                                h16x2 w00, h16x2 w01, h16x2 w10, h16x2 w11) {
  uint4 r;
#pragma unroll
  for (int j = 0; j < 4; j++) {
    h16x2 v = as_h2((&a.x)[j]) * w00;
    v += as_h2((&b.x)[j]) * w01;
    v += as_h2((&c.x)[j]) * w10;
    v += as_h2((&d.x)[j]) * w11;
    (&r.x)[j] = h2bits(v);
  }
  return r;
}

// ---- kernel 1: combined prep = transpose (blocks 0-511) + weff (512-655) ----
__global__ __launch_bounds__(256) void prep_k(const float* __restrict__ x,
                                              u16* __restrict__ xT,
                                              const float* __restrict__ w0,
                                              const float* __restrict__ w1,
                                              const float* __restrict__ wf,
                                              u16* __restrict__ weffg) {
  __shared__ float ws[84][32];    // w-slice [oc][kc]
  __shared__ float wfs[84][84];   // wf-slice [n][oc]
  const int blk = blockIdx.x;
  const int t = threadIdx.x;

  if (blk < 512) {
    // ---- transpose part: x f32 NCHW -> xT f16 NHWC ----
    const int b = blk >> 6, y = blk & 63;
    const int cg = t >> 4;
    const int w4 = (t & 15) * 4;
    const float* xp = x + ((size_t)(b * 128) * 64 + y) * 64;
    u16* op = xT + ((size_t)(b * 64 + y) * 64) * 128;
    float4 v[8];
#pragma unroll
    for (int k = 0; k < 8; k++)
      v[k] = *(const float4*)(xp + (size_t)(cg * 8 + k) * 4096 + w4);
#pragma unroll
    for (int ww = 0; ww < 4; ww++) {
      u32 rr[4];
#pragma unroll
      for (int p = 0; p < 4; p++)
        rr[p] = pack2h(((const float*)&v[2 * p])[ww], ((const float*)&v[2 * p + 1])[ww]);
      uint4 r;
      r.x = rr[0]; r.y = rr[1]; r.z = rr[2]; r.w = rr[3];
      *(uint4*)(op + (size_t)(w4 + ww) * 128 + cg * 8) = r;
    }
    return;
  }

  // ---- weff part ----
  const int wblk = blk - 512;        // 0..143
  const int ks = wblk >> 1, nh = wblk & 1;
  const int br = ks >= 36 ? 1 : 0;
  const int ksb = ks - br * 36;
  const int tap = ksb >> 2, chunk = ksb & 3;
  const float* w = br ? w1 : w0;
  for (int i = t; i < 2688; i += 256) {
    int oc = i >> 5, kc = i & 31;
    ws[oc][kc] = w[oc * 1152 + (chunk * 32 + kc) * 9 + tap];
  }
  for (int i = t; i < 7056; i += 256) {
    int n = i / 84, oc = i - n * 84;
    wfs[n][oc] = wf[n * 168 + br * 84 + oc];
  }
  __syncthreads();

  const int kc = t & 31, ng = t >> 5;   // ng 0..7
  const int n0 = nh * 48 + ng * 6;
  int nc[6];
  bool nv[6];
#pragma unroll
  for (int i = 0; i < 6; i++) {
    int n = n0 + i;
    nv[i] = n < 84;
    nc[i] = min(n, 83);
  }
  float accv[6] = {0.f, 0.f, 0.f, 0.f, 0.f, 0.f};
#pragma unroll 4
  for (int oc = 0; oc < 84; oc++) {
    float wv_ = ws[oc][kc];
#pragma unroll
    for (int i = 0; i < 6; i++) accv[i] += wfs[nc[i]][oc] * wv_;
  }
#pragma unroll
  for (int i = 0; i < 6; i++) {
    int n = n0 + i;
    int nt = n >> 4, lrow = n & 15, lg = kc >> 3, j = kc & 7;
    int idx = ((ks * 6 + nt) * 64 + lg * 16 + lrow) * 8 + j;
    weffg[idx] = f2h(nv[i] ? accv[i] : 0.f);
  }
}

// ---- kernel 2: LDS-window deform-sample + GEMM (r19 core + early-issue) -----
// r21 vs r19 (r20's swizzle reverted -- conflicts rose and time was flat, so
// LDS conflicts are not critical-path): blend ALL 4 fragments at the top of
// the tap (q dies immediately), then issue the next tap's 16 ds_reads BEFORE
// either MFMA cluster -> gather latency covered by 24 MFMAs + 2 weff loads
// (was 12). Register peak unchanged (a2/a3 take dead q slots).
// 512 blocks = (b:8 -> XCD) x (h:64), 512 threads (8 waves).
// Wave wv: pxh = wv>>2 (32-px half), br = (wv>>1)&1, cp = wv&1 (K quarter).
__global__ __launch_bounds__(512, 1) void deform_main(
    const u16* __restrict__ xT, const u16* __restrict__ weffg,
    const float* __restrict__ dm0, const float* __restrict__ dm1,
    const float* __restrict__ bias, float* __restrict__ out) {
  __shared__ uint4 ldsbuf[9360];   // 9 rows * 16 slots * 65 * 16B = 146.25 KiB

  const int t = threadIdx.x;
  const int wv = t >> 6, lane = t & 63;
  const int pxh = wv >> 2, br = (wv >> 1) & 1, cp = wv & 1;
  const int lrow = lane & 15, lg = lane >> 4;
  const int blk = blockIdx.x;
  const int b = blk & 7, h = blk >> 3;
  const int px0 = pxh * 32;

  const u16* xb = xT + (size_t)b * 524288;

  // ---- stage rows [h-4, h+4] into LDS (coalesced 16B, 18 iters/thread) ----
#pragma unroll
  for (int k = 0; k < 18; k++) {
    int u = t + (k << 9);          // < 9216
    int i = u >> 10;               // window row 0..8
    int ul = u & 1023;             // x*16 + slot
    int ysr = min(63, max(0, h - 4 + i));
    uint4 v = *(const uint4*)(xb + ysr * 8192 + ul * 8);
    int s = ul & 15, xx = ul >> 4;
    ldsbuf[(i * 16 + s) * 65 + xx] = v;
  }
  __syncthreads();

  const float* dmb = (br ? dm1 : dm0) + (size_t)b * 73728 + h * 64 + px0 + lrow;
  const u16* wbase = weffg + (size_t)(br * 36 + cp * 2) * 3072 + lane * 8;

  f32x4 acc[6][2];
#pragma unroll
  for (int i = 0; i < 6; i++)
#pragma unroll
    for (int f = 0; f < 2; f++) acc[i][f] = f32x4{0.f, 0.f, 0.f, 0.f};

  h16x2 w00h[2], w01h[2], w10h[2], w11h[2];
  int x0a[2], x1a[2], yw0a[2], yw1a[2];   // yw*: window-relative rows (may be OOW)
  float dyN[2], dxN[2];
  uint4 q[16];                            // [c][f][corner] in flight (1 tap ahead)
  uint4 wA0, wA1, wA2, wA3, wA4, wA5;     // weff ping
  uint4 wB0, wB1, wB2, wB3, wB4, wB5;     // weff pong

  auto tapstate = [&](int f, int ty, int tx, float dy, float dx) {
    float pyf = (float)(h + ty - 1) + dy;
    float pxf = (float)(px0 + f * 16 + lrow + tx - 1) + dx;
    float y0f = floorf(pyf), x0f = floorf(pxf);
    int y0 = (int)y0f, x0 = (int)x0f;
    float wy1 = pyf - y0f, wx1 = pxf - x0f;
    float wy0 = 1.f - wy1, wx0 = 1.f - wx1;
    int y1 = y0 + 1, x1 = x0 + 1;
    wy0 *= ((u32)y0 < 64u) ? 1.f : 0.f;
    wy1 *= ((u32)y1 < 64u) ? 1.f : 0.f;
    wx0 *= ((u32)x0 < 64u) ? 1.f : 0.f;
    wx1 *= ((u32)x1 < 64u) ? 1.f : 0.f;
    _Float16 a00 = (_Float16)(wy0 * wx0), a01 = (_Float16)(wy0 * wx1);
    _Float16 a10 = (_Float16)(wy1 * wx0), a11 = (_Float16)(wy1 * wx1);
    w00h[f] = h16x2{a00, a00}; w01h[f] = h16x2{a01, a01};
    w10h[f] = h16x2{a10, a10}; w11h[f] = h16x2{a11, a11};
    int y0c = min(63, max(0, y0)), y1c = min(63, max(0, y1));
    x0a[f] = min(63, max(0, x0));
    x1a[f] = min(63, max(0, x1));
    yw0a[f] = y0c - h + 4;                // in-window iff 0..8
    yw1a[f] = y1c - h + 4;
  };

  // issue all 16 ds_read corners for the current tap
  auto issue_lds = [&]() {
#pragma unroll
    for (int c = 0; c < 2; c++) {
      int slot = cp * 8 + c * 4 + lg;
#pragma unroll
      for (int f = 0; f < 2; f++) {
        int y0w = min(8, max(0, yw0a[f]));
        int y1w = min(8, max(0, yw1a[f]));
        int b0 = (y0w * 16 + slot) * 65;
        int b1 = (y1w * 16 + slot) * 65;
        q[c * 8 + f * 4 + 0] = ldsbuf[b0 + x0a[f]];
        q[c * 8 + f * 4 + 1] = ldsbuf[b0 + x1a[f]];
        q[c * 8 + f * 4 + 2] = ldsbuf[b1 + x0a[f]];
        q[c * 8 + f * 4 + 3] = ldsbuf[b1 + x1a[f]];
      }
    }
  };

  // rare out-of-window fallback: predicated global corner loads (xT is f16)
  auto oow_fix = [&]() {
    bool bad = ((u32)yw0a[0] > 8u) | ((u32)yw1a[0] > 8u) |
               ((u32)yw0a[1] > 8u) | ((u32)yw1a[1] > 8u);
    if (__any(bad)) {
#pragma unroll
      for (int f = 0; f < 2; f++) {
        if ((u32)yw0a[f] > 8u) {
          const u16* p = xb + (yw0a[f] + h - 4) * 8192 + cp * 64 + lg * 8;
#pragma unroll
          for (int c = 0; c < 2; c++) {
            q[c * 8 + f * 4 + 0] = *(const uint4*)(p + c * 32 + x0a[f] * 128);
            q[c * 8 + f * 4 + 1] = *(const uint4*)(p + c * 32 + x1a[f] * 128);
          }
        }
        if ((u32)yw1a[f] > 8u) {
          const u16* p = xb + (yw1a[f] + h - 4) * 8192 + cp * 64 + lg * 8;
#pragma unroll
          for (int c = 0; c < 2; c++) {
            q[c * 8 + f * 4 + 2] = *(const uint4*)(p + c * 32 + x0a[f] * 128);
            q[c * 8 + f * 4 + 3] = *(const uint4*)(p + c * 32 + x1a[f] * 128);
          }
        }
      }
    }
  };

  // ---- prologue: tap 0 state + reads, dm(tap1), weff step0 ----
  {
    float dy0 = dmb[0], dx0 = dmb[4096];
    float dy1 = dmb[16], dx1 = dmb[4096 + 16];
    tapstate(0, 0, 0, dy0, dx0);
    tapstate(1, 0, 0, dy1, dx1);
  }
  issue_lds();
  oow_fix();
  dyN[0] = dmb[2 * 4096];      dxN[0] = dmb[3 * 4096];
  dyN[1] = dmb[2 * 4096 + 16]; dxN[1] = dmb[3 * 4096 + 16];
  {
    const u16* wp = wbase;   // (tap0, c0)
    wA0 = *(const uint4*)(wp);        wA1 = *(const uint4*)(wp + 512);
    wA2 = *(const uint4*)(wp + 1024); wA3 = *(const uint4*)(wp + 1536);
    wA4 = *(const uint4*)(wp + 2048); wA5 = *(const uint4*)(wp + 2560);
  }

#pragma unroll 1
  for (int tap = 0; tap < 9; tap++) {
    // weff chunk 1 for this tap (consumed by the second MFMA cluster)
    {
      const u16* wpB = wbase + (size_t)(tap * 4 + 1) * 3072;
      wB0 = *(const uint4*)(wpB);        wB1 = *(const uint4*)(wpB + 512);
      wB2 = *(const uint4*)(wpB + 1024); wB3 = *(const uint4*)(wpB + 1536);
      wB4 = *(const uint4*)(wpB + 2048); wB5 = *(const uint4*)(wpB + 2560);
    }

    // blend ALL 4 fragments now -- q is dead after this point
    uint4 a0 = blend4h(q[0], q[1], q[2], q[3], w00h[0], w01h[0], w10h[0], w11h[0]);
    uint4 a1 = blend4h(q[4], q[5], q[6], q[7], w00h[1], w01h[1], w10h[1], w11h[1]);
    uint4 a2 = blend4h(q[8], q[9], q[10], q[11], w00h[0], w01h[0], w10h[0], w11h[0]);
    uint4 a3 = blend4h(q[12], q[13], q[14], q[15], w00h[1], w01h[1], w10h[1], w11h[1]);

    // issue NEXT tap's gathers before any MFMA: 24 MFMAs + weff loads of cover
    if (tap < 8) {
      int tn = tap + 1;
      int ty = (tn * 11) >> 5;     // tn/3
      int tx = tn - ty * 3;
      tapstate(0, ty, tx, dyN[0], dxN[0]);
      tapstate(1, ty, tx, dyN[1], dxN[1]);
      issue_lds();
      oow_fix();
      if (tap < 7) {
        dyN[0] = dmb[(2 * tn + 2) * 4096];      dxN[0] = dmb[(2 * tn + 3) * 4096];
        dyN[1] = dmb[(2 * tn + 2) * 4096 + 16]; dxN[1] = dmb[(2 * tn + 3) * 4096 + 16];
      }
    }

    // ---- MFMA cluster c=0 (wA) ----
    {
      f16x8 af0 = as_h8(a0), af1 = as_h8(a1);
      __builtin_amdgcn_s_setprio(1);
      acc[0][0] = __builtin_amdgcn_mfma_f32_16x16x32_f16(as_h8(wA0), af0, acc[0][0], 0, 0, 0);
      acc[1][0] = __builtin_amdgcn_mfma_f32_16x16x32_f16(as_h8(wA1), af0, acc[1][0], 0, 0, 0);
      acc[2][0] = __builtin_amdgcn_mfma_f32_16x16x32_f16(as_h8(wA2), af0, acc[2][0], 0, 0, 0);
      acc[3][0] = __builtin_amdgcn_mfma_f32_16x16x32_f16(as_h8(wA3), af0, acc[3][0], 0, 0, 0);
      acc[4][0] = __builtin_amdgcn_mfma_f32_16x16x32_f16(as_h8(wA4), af0, acc[4][0], 0, 0, 0);
      acc[5][0] = __builtin_amdgcn_mfma_f32_16x16x32_f16(as_h8(wA5), af0, acc[5][0], 0, 0, 0);
      acc[0][1] = __builtin_amdgcn_mfma_f32_16x16x32_f16(as_h8(wA0), af1, acc[0][1], 0, 0, 0);
      acc[1][1] = __builtin_amdgcn_mfma_f32_16x16x32_f16(as_h8(wA1), af1, acc[1][1], 0, 0, 0);
      acc[2][1] = __builtin_amdgcn_mfma_f32_16x16x32_f16(as_h8(wA2), af1, acc[2][1], 0, 0, 0);
      acc[3][1] = __builtin_amdgcn_mfma_f32_16x16x32_f16(as_h8(wA3), af1, acc[3][1], 0, 0, 0);
      acc[4][1] = __builtin_amdgcn_mfma_f32_16x16x32_f16(as_h8(wA4), af1, acc[4][1], 0, 0, 0);
      acc[5][1] = __builtin_amdgcn_mfma_f32_16x16x32_f16(as_h8(wA5), af1, acc[5][1], 0, 0, 0);
      __builtin_amdgcn_s_setprio(0);
    }

    // weff chunk 0 of NEXT tap (ping refill, covered by MFMA c=1)
    if (tap < 8) {
      const u16* wpA = wbase + (size_t)((tap + 1) * 4) * 3072;
      wA0 = *(const uint4*)(wpA);        wA1 = *(const uint4*)(wpA + 512);
      wA2 = *(const uint4*)(wpA + 1024); wA3 = *(const uint4*)(wpA + 1536);
      wA4 = *(const uint4*)(wpA + 2048); wA5 = *(const uint4*)(wpA + 2560);
    }

    // ---- MFMA cluster c=1 (wB) ----
    {
      f16x8 af2 = as_h8(a2), af3 = as_h8(a3);
      __builtin_amdgcn_s_setprio(1);
      acc[0][0] = __builtin_amdgcn_mfma_f32_16x16x32_f16(as_h8(wB0), af2, acc[0][0], 0, 0, 0);
      acc[1][0] = __builtin_amdgcn_mfma_f32_16x16x32_f16(as_h8(wB1), af2, acc[1][0], 0, 0, 0);
      acc[2][0] = __builtin_amdgcn_mfma_f32_16x16x32_f16(as_h8(wB2), af2, acc[2][0], 0, 0, 0);
      acc[3][0] = __builtin_amdgcn_mfma_f32_16x16x32_f16(as_h8(wB3), af2, acc[3][0], 0, 0, 0);
      acc[4][0] = __builtin_amdgcn_mfma_f32_16x16x32_f16(as_h8(wB4), af2, acc[4][0], 0, 0, 0);
      acc[5][0] = __builtin_amdgcn_mfma_f32_16x16x32_f16(as_h8(wB5), af2, acc[5][0], 0, 0, 0);
      acc[0][1] = __builtin_amdgcn_mfma_f32_16x16x32_f16(as_h8(wB0), af3, acc[0][1], 0, 0, 0);
      acc[1][1] = __builtin_amdgcn_mfma_f32_16x16x32_f16(as_h8(wB1), af3, acc[1][1], 0, 0, 0);
      acc[2][1] = __builtin_amdgcn_mfma_f32_16x16x32_f16(as_h8(wB2), af3, acc[2][1], 0, 0, 0);
      acc[3][1] = __builtin_amdgcn_mfma_f32_16x16x32_f16(as_h8(wB3), af3, acc[3][1], 0, 0, 0);
      acc[4][1] = __builtin_amdgcn_mfma_f32_16x16x32_f16(as_h8(wB4), af3, acc[4][1], 0, 0, 0);
      acc[5][1] = __builtin_amdgcn_mfma_f32_16x16x32_f16(as_h8(wB5), af3, acc[5][1], 0, 0, 0);
      __builtin_amdgcn_s_setprio(0);
    }
  }

  // ---- reduce the 4 K-partials per px-half (reuse staging LDS), store ----
  __syncthreads();                       // all LDS gather reads done
  const int sub = wv & 3;                // br*2+cp
  const int rbase = pxh * 2304;          // uint4 units; 2*2304 = 4608 <= 9360
  if (sub > 0) {
#pragma unroll
    for (int nt = 0; nt < 6; nt++)
#pragma unroll
      for (int f = 0; f < 2; f++) {
        uint4 v;
        __builtin_memcpy(&v, &acc[nt][f], 16);
        ldsbuf[rbase + ((sub - 1) * 12 + nt * 2 + f) * 64 + lane] = v;
      }
  }
  __syncthreads();
  if (sub == 0) {
#pragma unroll
    for (int nt = 0; nt < 6; nt++)
#pragma unroll
      for (int f = 0; f < 2; f++) {
#pragma unroll
        for (int r = 0; r < 3; r++) {
          uint4 v = ldsbuf[rbase + (r * 12 + nt * 2 + f) * 64 + lane];
          f32x4 fv;
          __builtin_memcpy(&fv, &v, 16);
#pragma unroll
          for (int j = 0; j < 4; j++) acc[nt][f][j] += fv[j];
        }
      }
    float* op = out + ((size_t)b * 84 * 64 + h) * 64 + px0;
#pragma unroll
    for (int nt = 0; nt < 6; nt++)
#pragma unroll
      for (int j = 0; j < 4; j++) {
        int o = nt * 16 + lg * 4 + j;
        if (o < 84) {
          float bv = bias[o];
#pragma unroll
          for (int f = 0; f < 2; f++)
            op[(size_t)o * 4096 + f * 16 + lrow] = acc[nt][f][j] + bv;
        }
      }
  }
}

// ---- launch -----------------------------------------------------------------
extern "C" void kernel_launch(void* const* d_in, const int* in_sizes, int n_in,
                              void* d_out, int out_size, void* d_ws, size_t ws_size,
                              hipStream_t stream) {
  const float* x   = (const float*)d_in[0];
  const float* dm0 = (const float*)d_in[1];
  const float* dm1 = (const float*)d_in[2];
  const float* w0  = (const float*)d_in[3];
  const float* w1  = (const float*)d_in[4];
  const float* wf  = (const float*)d_in[5];
  const float* bf  = (const float*)d_in[6];
  float* out = (float*)d_out;

  u16* xT = (u16*)d_ws;                                               // 8 MiB
  u16* weffg = (u16*)((char*)d_ws + (size_t)8 * 64 * 64 * 128 * 2);   // 432 KiB

  prep_k<<<656, 256, 0, stream>>>(x, xT, w0, w1, wf, weffg);
  deform_main<<<512, 512, 0, stream>>>(xT, weffg, dm0, dm1, bf, out);
}

// Round 23
// 53.500 us; speedup vs baseline: 1.6676x; 1.6676x over previous
//
#include <hip/hip_runtime.h>
#include <hip/hip_fp16.h>
#include <hip/hip_bf16.h>

using u16 = unsigned short;
using u32 = unsigned int;
typedef float f32x4 __attribute__((ext_vector_type(4)));
typedef _Float16 h16x2 __attribute__((ext_vector_type(2)));
typedef _Float16 f16x8 __attribute__((ext_vector_type(8)));

// ---- helpers ----------------------------------------------------------------
// RNE f32 -> f16 bits
static __device__ __forceinline__ u16 f2h(float f) {
  __half h = __float2half(f);
  u16 r;
  __builtin_memcpy(&r, &h, 2);
  return r;
}

// RNE pack of two f32 -> f16x2 (a in low half)
static __device__ __forceinline__ u32 pack2h(float a, float b) {
  return (u32)f2h(a) | ((u32)f2h(b) << 16);
}

static __device__ __forceinline__ f16x8 as_h8(uint4 v) {
  f16x8 r;
  __builtin_memcpy(&r, &v, 16);
  return r;
}

static __device__ __forceinline__ h16x2 as_h2(u32 v) {
  h16x2 r;
  __builtin_memcpy(&r, &v, 4);
  return r;
}

static __device__ __forceinline__ u32 h2bits(h16x2 v) {
  u32 r;
  __builtin_memcpy(&r, &v, 4);
  return r;
}

// 4-corner bilinear blend of 8 f16 channels, fully packed-f16 math:
// per word = 1 v_pk_mul_f16 + 3 v_pk_fma_f16.
static __device__ __forceinline__ uint4 blend4h(uint4 a, uint4 b, uint4 c, uint4 d,
                                                h16x2 w00, h16x2 w01, h16x2 w10, h16x2 w11) {
  uint4 r;
#pragma unroll
  for (int j = 0; j < 4; j++) {
    h16x2 v = as_h2((&a.x)[j]) * w00;
    v += as_h2((&b.x)[j]) * w01;
    v += as_h2((&c.x)[j]) * w10;
    v += as_h2((&d.x)[j]) * w11;
    (&r.x)[j] = h2bits(v);
  }
  return r;
}

// ---- kernel 1: combined prep = transpose (blocks 0-511) + weff (512-655) ----
// Transpose: x [B,C,H,W] f32 -> xT [B,H,W,C] f16, float4 loads.
// weff: fully-LDS inner loop, output f16, fragment layout:
// element idx = ((ks*6+nt)*64+lg*16+lrow)*8+j, n=nt*16+lrow, kc=lg*8+j.
__global__ __launch_bounds__(256) void prep_k(const float* __restrict__ x,
                                              u16* __restrict__ xT,
                                              const float* __restrict__ w0,
                                              const float* __restrict__ w1,
                                              const float* __restrict__ wf,
                                              u16* __restrict__ weffg) {
  __shared__ float ws[84][32];    // w-slice [oc][kc]
  __shared__ float wfs[84][84];   // wf-slice [n][oc]
  const int blk = blockIdx.x;
  const int t = threadIdx.x;

  if (blk < 512) {
    // ---- transpose part ----
    const int b = blk >> 6, y = blk & 63;
    const int cg = t >> 4;
    const int w4 = (t & 15) * 4;
    const float* xp = x + ((size_t)(b * 128) * 64 + y) * 64;
    u16* op = xT + ((size_t)(b * 64 + y) * 64) * 128;
    float4 v[8];
#pragma unroll
    for (int k = 0; k < 8; k++)
      v[k] = *(const float4*)(xp + (size_t)(cg * 8 + k) * 4096 + w4);
#pragma unroll
    for (int ww = 0; ww < 4; ww++) {
      u32 rr[4];
#pragma unroll
      for (int p = 0; p < 4; p++)
        rr[p] = pack2h(((const float*)&v[2 * p])[ww], ((const float*)&v[2 * p + 1])[ww]);
      uint4 r;
      r.x = rr[0]; r.y = rr[1]; r.z = rr[2]; r.w = rr[3];
      *(uint4*)(op + (size_t)(w4 + ww) * 128 + cg * 8) = r;
    }
    return;
  }

  // ---- weff part ----
  const int wblk = blk - 512;        // 0..143
  const int ks = wblk >> 1, nh = wblk & 1;
  const int br = ks >= 36 ? 1 : 0;
  const int ksb = ks - br * 36;
  const int tap = ksb >> 2, chunk = ksb & 3;
  const float* w = br ? w1 : w0;
  for (int i = t; i < 2688; i += 256) {
    int oc = i >> 5, kc = i & 31;
    ws[oc][kc] = w[oc * 1152 + (chunk * 32 + kc) * 9 + tap];
  }
  for (int i = t; i < 7056; i += 256) {
    int n = i / 84, oc = i - n * 84;
    wfs[n][oc] = wf[n * 168 + br * 84 + oc];
  }
  __syncthreads();

  const int kc = t & 31, ng = t >> 5;   // ng 0..7
  const int n0 = nh * 48 + ng * 6;
  int nc[6];
  bool nv[6];
#pragma unroll
  for (int i = 0; i < 6; i++) {
    int n = n0 + i;
    nv[i] = n < 84;
    nc[i] = min(n, 83);
  }
  float accv[6] = {0.f, 0.f, 0.f, 0.f, 0.f, 0.f};
#pragma unroll 4
  for (int oc = 0; oc < 84; oc++) {
    float wv_ = ws[oc][kc];
#pragma unroll
    for (int i = 0; i < 6; i++) accv[i] += wfs[nc[i]][oc] * wv_;
  }
#pragma unroll
  for (int i = 0; i < 6; i++) {
    int n = n0 + i;
    int nt = n >> 4, lrow = n & 15, lg = kc >> 3, j = kc & 7;
    int idx = ((ks * 6 + nt) * 64 + lg * 16 + lrow) * 8 + j;
    weffg[idx] = f2h(nv[i] ? accv[i] : 0.f);
  }
}

// ---- kernel 2: LDS-resident row-window deform-sample + GEMM (r19 verbatim) --
// Best measured configuration (total 53.8us): r10 structure + f16 packed
// blend (v_pk_fma_f16) + mfma_f32_16x16x32_f16. r20's swizzle and r21's
// issue-early reorder both measured negative. r22's post-timing divergence
// was a replay-only flake (identical source passed r19/r20/r21); clean retest.
// 512 blocks = (b:8 -> XCD) x (h:64), 512 threads (8 waves).
// Wave wv: pxh = wv>>2 (32-px half), br = (wv>>1)&1, cp = wv&1 (K quarter).
__global__ __launch_bounds__(512, 1) void deform_main(
    const u16* __restrict__ xT, const u16* __restrict__ weffg,
    const float* __restrict__ dm0, const float* __restrict__ dm1,
    const float* __restrict__ bias, float* __restrict__ out) {
  __shared__ uint4 ldsbuf[9360];   // 9 rows * 16 slots * 65 * 16B = 146.25 KiB

  const int t = threadIdx.x;
  const int wv = t >> 6, lane = t & 63;
  const int pxh = wv >> 2, br = (wv >> 1) & 1, cp = wv & 1;
  const int lrow = lane & 15, lg = lane >> 4;
  const int blk = blockIdx.x;
  const int b = blk & 7, h = blk >> 3;
  const int px0 = pxh * 32;

  const u16* xb = xT + (size_t)b * 524288;

  // ---- stage rows [h-4, h+4] into LDS (coalesced 16B, 18 iters/thread) ----
#pragma unroll
  for (int k = 0; k < 18; k++) {
    int u = t + (k << 9);          // < 9216
    int i = u >> 10;               // window row 0..8
    int ul = u & 1023;             // x*16 + slot
    int ysr = min(63, max(0, h - 4 + i));
    uint4 v = *(const uint4*)(xb + ysr * 8192 + ul * 8);
    int s = ul & 15, xx = ul >> 4;
    ldsbuf[(i * 16 + s) * 65 + xx] = v;
  }
  __syncthreads();

  const float* dmb = (br ? dm1 : dm0) + (size_t)b * 73728 + h * 64 + px0 + lrow;
  const u16* wbase = weffg + (size_t)(br * 36 + cp * 2) * 3072 + lane * 8;

  f32x4 acc[6][2];
#pragma unroll
  for (int i = 0; i < 6; i++)
#pragma unroll
    for (int f = 0; f < 2; f++) acc[i][f] = f32x4{0.f, 0.f, 0.f, 0.f};

  h16x2 w00h[2], w01h[2], w10h[2], w11h[2];
  int x0a[2], x1a[2], yw0a[2], yw1a[2];   // yw*: window-relative rows (may be OOW)
  float dyN[2], dxN[2];
  uint4 q[16];                            // [c][f][corner] in flight (1 tap ahead)
  uint4 wA0, wA1, wA2, wA3, wA4, wA5;     // weff ping
  uint4 wB0, wB1, wB2, wB3, wB4, wB5;     // weff pong

  auto tapstate = [&](int f, int ty, int tx, float dy, float dx) {
    float pyf = (float)(h + ty - 1) + dy;
    float pxf = (float)(px0 + f * 16 + lrow + tx - 1) + dx;
    float y0f = floorf(pyf), x0f = floorf(pxf);
    int y0 = (int)y0f, x0 = (int)x0f;
    float wy1 = pyf - y0f, wx1 = pxf - x0f;
    float wy0 = 1.f - wy1, wx0 = 1.f - wx1;
    int y1 = y0 + 1, x1 = x0 + 1;
    wy0 *= ((u32)y0 < 64u) ? 1.f : 0.f;
    wy1 *= ((u32)y1 < 64u) ? 1.f : 0.f;
    wx0 *= ((u32)x0 < 64u) ? 1.f : 0.f;
    wx1 *= ((u32)x1 < 64u) ? 1.f : 0.f;
    _Float16 a00 = (_Float16)(wy0 * wx0), a01 = (_Float16)(wy0 * wx1);
    _Float16 a10 = (_Float16)(wy1 * wx0), a11 = (_Float16)(wy1 * wx1);
    w00h[f] = h16x2{a00, a00}; w01h[f] = h16x2{a01, a01};
    w10h[f] = h16x2{a10, a10}; w11h[f] = h16x2{a11, a11};
    int y0c = min(63, max(0, y0)), y1c = min(63, max(0, y1));
    x0a[f] = min(63, max(0, x0));
    x1a[f] = min(63, max(0, x1));
    yw0a[f] = y0c - h + 4;                // in-window iff 0..8
    yw1a[f] = y1c - h + 4;
  };

  // issue all 16 ds_read corners for the current tap
  auto issue_lds = [&]() {
#pragma unroll
    for (int c = 0; c < 2; c++) {
      int slot = cp * 8 + c * 4 + lg;
#pragma unroll
      for (int f = 0; f < 2; f++) {
        int y0w = min(8, max(0, yw0a[f]));
        int y1w = min(8, max(0, yw1a[f]));
        int b0 = (y0w * 16 + slot) * 65;
        int b1 = (y1w * 16 + slot) * 65;
        q[c * 8 + f * 4 + 0] = ldsbuf[b0 + x0a[f]];
        q[c * 8 + f * 4 + 1] = ldsbuf[b0 + x1a[f]];
        q[c * 8 + f * 4 + 2] = ldsbuf[b1 + x0a[f]];
        q[c * 8 + f * 4 + 3] = ldsbuf[b1 + x1a[f]];
      }
    }
  };

  // rare out-of-window fallback: predicated global corner loads (xT is f16)
  auto oow_fix = [&]() {
    bool bad = ((u32)yw0a[0] > 8u) | ((u32)yw1a[0] > 8u) |
               ((u32)yw0a[1] > 8u) | ((u32)yw1a[1] > 8u);
    if (__any(bad)) {
#pragma unroll
      for (int f = 0; f < 2; f++) {
        if ((u32)yw0a[f] > 8u) {
          const u16* p = xb + (yw0a[f] + h - 4) * 8192 + cp * 64 + lg * 8;
#pragma unroll
          for (int c = 0; c < 2; c++) {
            q[c * 8 + f * 4 + 0] = *(const uint4*)(p + c * 32 + x0a[f] * 128);
            q[c * 8 + f * 4 + 1] = *(const uint4*)(p + c * 32 + x1a[f] * 128);
          }
        }
        if ((u32)yw1a[f] > 8u) {
          const u16* p = xb + (yw1a[f] + h - 4) * 8192 + cp * 64 + lg * 8;
#pragma unroll
          for (int c = 0; c < 2; c++) {
            q[c * 8 + f * 4 + 2] = *(const uint4*)(p + c * 32 + x0a[f] * 128);
            q[c * 8 + f * 4 + 3] = *(const uint4*)(p + c * 32 + x1a[f] * 128);
          }
        }
      }
    }
  };

  // ---- prologue: tap 0 state + reads, dm(tap1), weff step0 ----
  {
    float dy0 = dmb[0], dx0 = dmb[4096];
    float dy1 = dmb[16], dx1 = dmb[4096 + 16];
    tapstate(0, 0, 0, dy0, dx0);
    tapstate(1, 0, 0, dy1, dx1);
  }
  issue_lds();
  oow_fix();
  dyN[0] = dmb[2 * 4096];      dxN[0] = dmb[3 * 4096];
  dyN[1] = dmb[2 * 4096 + 16]; dxN[1] = dmb[3 * 4096 + 16];
  {
    const u16* wp = wbase;   // (tap0, c0)
    wA0 = *(const uint4*)(wp);        wA1 = *(const uint4*)(wp + 512);
    wA2 = *(const uint4*)(wp + 1024); wA3 = *(const uint4*)(wp + 1536);
    wA4 = *(const uint4*)(wp + 2048); wA5 = *(const uint4*)(wp + 2560);
  }

#pragma unroll 1
  for (int tap = 0; tap < 9; tap++) {
    // ---- chunk c=0: consume wA ----
    {
      const u16* wpB = wbase + (size_t)(tap * 4 + 1) * 3072;
      wB0 = *(const uint4*)(wpB);        wB1 = *(const uint4*)(wpB + 512);
      wB2 = *(const uint4*)(wpB + 1024); wB3 = *(const uint4*)(wpB + 1536);
      wB4 = *(const uint4*)(wpB + 2048); wB5 = *(const uint4*)(wpB + 2560);

      uint4 a0 = blend4h(q[0], q[1], q[2], q[3], w00h[0], w01h[0], w10h[0], w11h[0]);
      uint4 a1 = blend4h(q[4], q[5], q[6], q[7], w00h[1], w01h[1], w10h[1], w11h[1]);
      f16x8 af0 = as_h8(a0), af1 = as_h8(a1);
      __builtin_amdgcn_s_setprio(1);
      acc[0][0] = __builtin_amdgcn_mfma_f32_16x16x32_f16(as_h8(wA0), af0, acc[0][0], 0, 0, 0);
      acc[1][0] = __builtin_amdgcn_mfma_f32_16x16x32_f16(as_h8(wA1), af0, acc[1][0], 0, 0, 0);
      acc[2][0] = __builtin_amdgcn_mfma_f32_16x16x32_f16(as_h8(wA2), af0, acc[2][0], 0, 0, 0);
      acc[3][0] = __builtin_amdgcn_mfma_f32_16x16x32_f16(as_h8(wA3), af0, acc[3][0], 0, 0, 0);
      acc[4][0] = __builtin_amdgcn_mfma_f32_16x16x32_f16(as_h8(wA4), af0, acc[4][0], 0, 0, 0);
      acc[5][0] = __builtin_amdgcn_mfma_f32_16x16x32_f16(as_h8(wA5), af0, acc[5][0], 0, 0, 0);
      acc[0][1] = __builtin_amdgcn_mfma_f32_16x16x32_f16(as_h8(wA0), af1, acc[0][1], 0, 0, 0);
      acc[1][1] = __builtin_amdgcn_mfma_f32_16x16x32_f16(as_h8(wA1), af1, acc[1][1], 0, 0, 0);
      acc[2][1] = __builtin_amdgcn_mfma_f32_16x16x32_f16(as_h8(wA2), af1, acc[2][1], 0, 0, 0);
      acc[3][1] = __builtin_amdgcn_mfma_f32_16x16x32_f16(as_h8(wA3), af1, acc[3][1], 0, 0, 0);
      acc[4][1] = __builtin_amdgcn_mfma_f32_16x16x32_f16(as_h8(wA4), af1, acc[4][1], 0, 0, 0);
      acc[5][1] = __builtin_amdgcn_mfma_f32_16x16x32_f16(as_h8(wA5), af1, acc[5][1], 0, 0, 0);
      __builtin_amdgcn_s_setprio(0);
    }

    // ---- chunk c=1: consume wB ----
    {
      if (tap < 8) {
        const u16* wpA = wbase + (size_t)((tap + 1) * 4) * 3072;
        wA0 = *(const uint4*)(wpA);        wA1 = *(const uint4*)(wpA + 512);
        wA2 = *(const uint4*)(wpA + 1024); wA3 = *(const uint4*)(wpA + 1536);
        wA4 = *(const uint4*)(wpA + 2048); wA5 = *(const uint4*)(wpA + 2560);
      }

      uint4 a2 = blend4h(q[8], q[9], q[10], q[11], w00h[0], w01h[0], w10h[0], w11h[0]);
      uint4 a3 = blend4h(q[12], q[13], q[14], q[15], w00h[1], w01h[1], w10h[1], w11h[1]);

      // next tap: state + ds-issue (q now dead), dm prefetch 2 taps ahead
      if (tap < 8) {
        int tn = tap + 1;
        int ty = (tn * 11) >> 5;     // tn/3
        int tx = tn - ty * 3;
        tapstate(0, ty, tx, dyN[0], dxN[0]);
        tapstate(1, ty, tx, dyN[1], dxN[1]);
        issue_lds();
        oow_fix();
        if (tap < 7) {
          dyN[0] = dmb[(2 * tn + 2) * 4096];      dxN[0] = dmb[(2 * tn + 3) * 4096];
          dyN[1] = dmb[(2 * tn + 2) * 4096 + 16]; dxN[1] = dmb[(2 * tn + 3) * 4096 + 16];
        }
      }

      f16x8 af2 = as_h8(a2), af3 = as_h8(a3);
      __builtin_amdgcn_s_setprio(1);
      acc[0][0] = __builtin_amdgcn_mfma_f32_16x16x32_f16(as_h8(wB0), af2, acc[0][0], 0, 0, 0);
      acc[1][0] = __builtin_amdgcn_mfma_f32_16x16x32_f16(as_h8(wB1), af2, acc[1][0], 0, 0, 0);
      acc[2][0] = __builtin_amdgcn_mfma_f32_16x16x32_f16(as_h8(wB2), af2, acc[2][0], 0, 0, 0);
      acc[3][0] = __builtin_amdgcn_mfma_f32_16x16x32_f16(as_h8(wB3), af2, acc[3][0], 0, 0, 0);
      acc[4][0] = __builtin_amdgcn_mfma_f32_16x16x32_f16(as_h8(wB4), af2, acc[4][0], 0, 0, 0);
      acc[5][0] = __builtin_amdgcn_mfma_f32_16x16x32_f16(as_h8(wB5), af2, acc[5][0], 0, 0, 0);
      acc[0][1] = __builtin_amdgcn_mfma_f32_16x16x32_f16(as_h8(wB0), af3, acc[0][1], 0, 0, 0);
      acc[1][1] = __builtin_amdgcn_mfma_f32_16x16x32_f16(as_h8(wB1), af3, acc[1][1], 0, 0, 0);
      acc[2][1] = __builtin_amdgcn_mfma_f32_16x16x32_f16(as_h8(wB2), af3, acc[2][1], 0, 0, 0);
      acc[3][1] = __builtin_amdgcn_mfma_f32_16x16x32_f16(as_h8(wB3), af3, acc[3][1], 0, 0, 0);
      acc[4][1] = __builtin_amdgcn_mfma_f32_16x16x32_f16(as_h8(wB4), af3, acc[4][1], 0, 0, 0);
      acc[5][1] = __builtin_amdgcn_mfma_f32_16x16x32_f16(as_h8(wB5), af3, acc[5][1], 0, 0, 0);
      __builtin_amdgcn_s_setprio(0);
    }
  }

  // ---- reduce the 4 K-partials per px-half (reuse staging LDS), store ----
  __syncthreads();                       // all LDS gather reads done
  const int sub = wv & 3;                // br*2+cp
  const int rbase = pxh * 2304;          // uint4 units; 2*2304 = 4608 <= 9360
  if (sub > 0) {
#pragma unroll
    for (int nt = 0; nt < 6; nt++)
#pragma unroll
      for (int f = 0; f < 2; f++) {
        uint4 v;
        __builtin_memcpy(&v, &acc[nt][f], 16);
        ldsbuf[rbase + ((sub - 1) * 12 + nt * 2 + f) * 64 + lane] = v;
      }
  }
  __syncthreads();
  if (sub == 0) {
#pragma unroll
    for (int nt = 0; nt < 6; nt++)
#pragma unroll
      for (int f = 0; f < 2; f++) {
#pragma unroll
        for (int r = 0; r < 3; r++) {
          uint4 v = ldsbuf[rbase + (r * 12 + nt * 2 + f) * 64 + lane];
          f32x4 fv;
          __builtin_memcpy(&fv, &v, 16);
#pragma unroll
          for (int j = 0; j < 4; j++) acc[nt][f][j] += fv[j];
        }
      }
    float* op = out + ((size_t)b * 84 * 64 + h) * 64 + px0;
#pragma unroll
    for (int nt = 0; nt < 6; nt++)
#pragma unroll
      for (int j = 0; j < 4; j++) {
        int o = nt * 16 + lg * 4 + j;
        if (o < 84) {
          float bv = bias[o];
#pragma unroll
          for (int f = 0; f < 2; f++)
            op[(size_t)o * 4096 + f * 16 + lrow] = acc[nt][f][j] + bv;
        }
      }
  }
}

// ---- launch -----------------------------------------------------------------
extern "C" void kernel_launch(void* const* d_in, const int* in_sizes, int n_in,
                              void* d_out, int out_size, void* d_ws, size_t ws_size,
                              hipStream_t stream) {
  const float* x   = (const float*)d_in[0];
  const float* dm0 = (const float*)d_in[1];
  const float* dm1 = (const float*)d_in[2];
  const float* w0  = (const float*)d_in[3];
  const float* w1  = (const float*)d_in[4];
  const float* wf  = (const float*)d_in[5];
  const float* bf  = (const float*)d_in[6];
  float* out = (float*)d_out;

  u16* xT = (u16*)d_ws;                                               // 8 MiB
  u16* weffg = (u16*)((char*)d_ws + (size_t)8 * 64 * 64 * 128 * 2);   // 432 KiB

  prep_k<<<656, 256, 0, stream>>>(x, xT, w0, w1, wf, weffg);
  deform_main<<<512, 512, 0, stream>>>(xT, weffg, dm0, dm1, bf, out);
}